// Round 9
// baseline (168.548 us; speedup 1.0000x reference)
//
#include <hip/hip_runtime.h>

#define T_LEN 262144
#define R_LEN 4000
#define NCH 64
#define NCHUNK 253       // B chunks t in [0,253); T[252] = zeros (clamp target)
#define SIG_M 48         // sigma(n) = (n>>5) + 48*(n&31); injective on n in [0,1536)
#define NSLOT 1536       // 1536 x 16B = 24576 B LDS
#define NSTEP 272        // multiple of 16 for full ring renaming; steps >=266 are zeros

typedef __attribute__((ext_vector_type(8))) short bf16x8;
typedef __attribute__((ext_vector_type(16))) float f32x16;

static __device__ __forceinline__ unsigned short f2bf(float f) {
  unsigned u = __builtin_bit_cast(unsigned, f);
  unsigned r = 0x7FFFu + ((u >> 16) & 1u);
  return (unsigned short)((u + r) >> 16);
}

// T[t][j,h,e] = k[4000 + j - 16t - 8h - e] (zero outside [0,4000))
// stored: btf[((ch*253 + t)*64 + lane)*8 + e], j = lane&31, h = lane>>5
__global__ __launch_bounds__(256) void build_btf(const float* __restrict__ src,
                                                 unsigned short* __restrict__ btf) {
  int t0 = blockIdx.x * 256 + threadIdx.x;
  if (t0 >= NCH * NCHUNK * 64) return;
  int lane = t0 & 63;
  int t = (t0 >> 6) % NCHUNK;
  int ch = t0 / (64 * NCHUNK);
  int j = lane & 31;
  int h = lane >> 5;
  int kbase = 4000 + j - 16 * t - 8 * h;
  const float* k = src + (size_t)ch * R_LEN;
  unsigned short vals[8];
#pragma unroll
  for (int e = 0; e < 8; ++e) {
    int r = kbase - e;
    float f = (r >= 0 && r < R_LEN) ? k[r] : 0.0f;
    vals[e] = f2bf(f);
  }
  unsigned int* dst = (unsigned int*)(btf + (size_t)t0 * 8);
  dst[0] = (unsigned int)vals[0] | ((unsigned int)vals[1] << 16);
  dst[1] = (unsigned int)vals[2] | ((unsigned int)vals[3] << 16);
  dst[2] = (unsigned int)vals[4] | ((unsigned int)vals[5] << 16);
  dst[3] = (unsigned int)vals[6] | ((unsigned int)vals[7] << 16);
}

// ONE WAVE per block (64 thr), __launch_bounds__(64,1): full 512-reg budget so the
// E/O depth-8 B-rings + depth-2 prefetch queues stay LIVE in registers (no reloads).
// ch = bid&63 (all pieces of a channel on XCD ch%8), piece = bid>>6, T0 = piece*8192.
// Outputs out[T0 + 256i + 32c + j], c in [0,8). D_c[i][j] = sum_q A_q[i] . T[q-2c].
// A_q lane(i=l31,h): x[T0-4000+256i+16q+8h+e]; block n = 32i+2q+h at LDS slot
// sigma(n) = (n>>5)+48*(n&31) -> A-reads = 2 contiguous 512B segments (conflict-free).
__global__ __launch_bounds__(64, 1) void conv_main(const float* __restrict__ x,
                                                   const unsigned short* __restrict__ btf,
                                                   float* __restrict__ out) {
  __shared__ alignas(16) unsigned char xs[NSLOT * 16];
  const int bid = blockIdx.x;
  const int ch = bid & 63;
  const int T0 = (bid >> 6) << 13;
  const float* xch = x + (size_t)ch * T_LEN;
  const char* btc = (const char*)btf + (size_t)ch * NCHUNK * 1024;

  const int lane = threadIdx.x;

  // ---- A staging: iterate permuted slot sig (contiguous LDS writes);
  // sig = a + 48b -> n = 32a + b; global reads scattered (L2 absorbs).
  for (int sig = lane; sig < NSLOT; sig += 64) {
    int b = sig / 48;
    int a = sig - 48 * b;
    int n = 32 * a + b;
    int gi = T0 - 4000 + 8 * n;
    float v0, v1, v2, v3, v4, v5, v6, v7;
    if (gi >= 0 && gi + 8 <= T_LEN) {
      float4 va = *(const float4*)(xch + gi);
      float4 vb = *(const float4*)(xch + gi + 4);
      v0 = va.x; v1 = va.y; v2 = va.z; v3 = va.w;
      v4 = vb.x; v5 = vb.y; v6 = vb.z; v7 = vb.w;
    } else {
      v0 = (gi + 0 >= 0 && gi + 0 < T_LEN) ? xch[gi + 0] : 0.f;
      v1 = (gi + 1 >= 0 && gi + 1 < T_LEN) ? xch[gi + 1] : 0.f;
      v2 = (gi + 2 >= 0 && gi + 2 < T_LEN) ? xch[gi + 2] : 0.f;
      v3 = (gi + 3 >= 0 && gi + 3 < T_LEN) ? xch[gi + 3] : 0.f;
      v4 = (gi + 4 >= 0 && gi + 4 < T_LEN) ? xch[gi + 4] : 0.f;
      v5 = (gi + 5 >= 0 && gi + 5 < T_LEN) ? xch[gi + 5] : 0.f;
      v6 = (gi + 6 >= 0 && gi + 6 < T_LEN) ? xch[gi + 6] : 0.f;
      v7 = (gi + 7 >= 0 && gi + 7 < T_LEN) ? xch[gi + 7] : 0.f;
    }
    uint4 pk;
    pk.x = (unsigned int)f2bf(v0) | ((unsigned int)f2bf(v1) << 16);
    pk.y = (unsigned int)f2bf(v2) | ((unsigned int)f2bf(v3) << 16);
    pk.z = (unsigned int)f2bf(v4) | ((unsigned int)f2bf(v5) << 16);
    pk.w = (unsigned int)f2bf(v6) | ((unsigned int)f2bf(v7) << 16);
    *(uint4*)(xs + 16 * sig) = pk;
  }
  __syncthreads();

  const int l31 = lane & 31;
  const int h = lane >> 5;
  const unsigned abase = 16u * (unsigned)l31;

  // n = 32*l31 + s, s = 2q+h -> sigma = l31 + (s>>5) + 48*(s&31)
  auto aread = [&](int q) -> bf16x8 {
    unsigned s = 2u * (unsigned)q + (unsigned)h;
    unsigned off = 16u * ((s >> 5) + (unsigned)SIG_M * (s & 31));
    return *(const bf16x8*)(xs + abase + off);
  };
  auto bloadz = [&](int t) -> bf16x8 {
    int tc = ((unsigned)t > 252u) ? 252 : t;   // negatives & >252 -> T[252] = zeros
    return *(const bf16x8*)(btc + (size_t)tc * 1024 + lane * 16);
  };

  f32x16 acc[8] = {};
  bf16x8 zero8 = {};
  // Ring state at step 0: E_c = T[-2c] (zeros for c>0), O_c = T[1-2c]
  bf16x8 E0 = bloadz(0), E1 = zero8, E2 = zero8, E3 = zero8,
         E4 = zero8, E5 = zero8, E6 = zero8, E7 = zero8;
  bf16x8 O0 = bloadz(1), O1 = zero8, O2 = zero8, O3 = zero8,
         O4 = zero8, O5 = zero8, O6 = zero8, O7 = zero8;
  // Prefetch queues (depth 2 per parity): pX0 = T[q+2], pX1 = T[q+4]
  bf16x8 pE0 = bloadz(2), pE1 = bloadz(4);
  bf16x8 pO0 = bloadz(3), pO1 = bloadz(5);
  bf16x8 a_cur = aread(0), a_nxt = aread(1);

#define DO_STEP(R0, R1, R2, R3, R4, R5, R6, R7, PP0, PP1, QQ)                            \
  {                                                                                      \
    bf16x8 nb = bloadz((QQ) + 6);  /* consumed 6 q-steps later */                        \
    bf16x8 an = aread((QQ) + 2);   /* A distance 2 */                                    \
    acc[0] = __builtin_amdgcn_mfma_f32_32x32x16_bf16(a_cur, R0, acc[0], 0, 0, 0);        \
    acc[1] = __builtin_amdgcn_mfma_f32_32x32x16_bf16(a_cur, R1, acc[1], 0, 0, 0);        \
    acc[2] = __builtin_amdgcn_mfma_f32_32x32x16_bf16(a_cur, R2, acc[2], 0, 0, 0);        \
    acc[3] = __builtin_amdgcn_mfma_f32_32x32x16_bf16(a_cur, R3, acc[3], 0, 0, 0);        \
    acc[4] = __builtin_amdgcn_mfma_f32_32x32x16_bf16(a_cur, R4, acc[4], 0, 0, 0);        \
    acc[5] = __builtin_amdgcn_mfma_f32_32x32x16_bf16(a_cur, R5, acc[5], 0, 0, 0);        \
    acc[6] = __builtin_amdgcn_mfma_f32_32x32x16_bf16(a_cur, R6, acc[6], 0, 0, 0);        \
    acc[7] = __builtin_amdgcn_mfma_f32_32x32x16_bf16(a_cur, R7, acc[7], 0, 0, 0);        \
    R7 = R6; R6 = R5; R5 = R4; R4 = R3; R3 = R2; R2 = R1; R1 = R0;                       \
    R0 = PP0; PP0 = PP1; PP1 = nb;                                                       \
    a_cur = a_nxt; a_nxt = an;                                                           \
  }

#pragma unroll 8
  for (int q = 0; q < NSTEP; q += 2) {
    DO_STEP(E0, E1, E2, E3, E4, E5, E6, E7, pE0, pE1, q);
    DO_STEP(O0, O1, O2, O3, O4, O5, O6, O7, pO0, pO1, q + 1);
  }
#undef DO_STEP

  // C/D layout: col j = lane&31, row i = (r&3) + 8*(r>>2) + 4*h
  float* och = out + (size_t)ch * T_LEN + T0;
#pragma unroll
  for (int c = 0; c < 8; ++c) {
#pragma unroll
    for (int r = 0; r < 16; ++r) {
      int irow = (r & 3) + 8 * (r >> 2) + 4 * h;
      och[256 * irow + 32 * c + l31] = acc[c][r];
    }
  }
}

extern "C" void kernel_launch(void* const* d_in, const int* in_sizes, int n_in,
                              void* d_out, int out_size, void* d_ws, size_t ws_size,
                              hipStream_t stream) {
  const float* onsets  = (const float*)d_in[0];
  const float* sources = (const float*)d_in[1];
  unsigned short* btf  = (unsigned short*)d_ws;   // 64*253*64*8*2 = 16,580,608 B
  float* out = (float*)d_out;

  int nthr = NCH * NCHUNK * 64;
  build_btf<<<(nthr + 255) / 256, 256, 0, stream>>>(sources, btf);
  conv_main<<<NCH * 32, 64, 0, stream>>>(onsets, btf, out);
}

// Round 10
// 120.868 us; speedup vs baseline: 1.3945x; 1.3945x over previous
//
#include <hip/hip_runtime.h>

#define T_LEN 262144
#define R_LEN 4000
#define NCH 64
#define NCHUNK 253       // B chunks t in [0,253); T[252] = zeros (clamp target)
#define WBLK 4616        // valid window 16B-blocks
#define SIG_M 145        // sigma(n) = (n>>5) + 145*(n&31), injective for n < 4640
#define NSLOT_W 4640     // sigma range; LDS = 4640*16 = 74240 B
#define NSTEP 272        // 17 x 16; steps >= 266 multiply pure-zero T chunks

typedef __attribute__((ext_vector_type(8))) short bf16x8;
typedef __attribute__((ext_vector_type(16))) float f32x16;

static __device__ __forceinline__ unsigned short f2bf(float f) {
  unsigned u = __builtin_bit_cast(unsigned, f);
  unsigned r = 0x7FFFu + ((u >> 16) & 1u);
  return (unsigned short)((u + r) >> 16);
}

// T[t][j,h,e] = k[4000 + j - 16t - 8h - e] (zero outside [0,4000))
// stored: btf[((ch*253 + t)*64 + lane)*8 + e], j = lane&31, h = lane>>5
__global__ __launch_bounds__(256) void build_btf(const float* __restrict__ src,
                                                 unsigned short* __restrict__ btf) {
  int t0 = blockIdx.x * 256 + threadIdx.x;
  if (t0 >= NCH * NCHUNK * 64) return;
  int lane = t0 & 63;
  int t = (t0 >> 6) % NCHUNK;
  int ch = t0 / (64 * NCHUNK);
  int j = lane & 31;
  int h = lane >> 5;
  int kbase = 4000 + j - 16 * t - 8 * h;
  const float* k = src + (size_t)ch * R_LEN;
  unsigned short vals[8];
#pragma unroll
  for (int e = 0; e < 8; ++e) {
    int r = kbase - e;
    float f = (r >= 0 && r < R_LEN) ? k[r] : 0.0f;
    vals[e] = f2bf(f);
  }
  unsigned int* dst = (unsigned int*)(btf + (size_t)t0 * 8);
  dst[0] = (unsigned int)vals[0] | ((unsigned int)vals[1] << 16);
  dst[1] = (unsigned int)vals[2] | ((unsigned int)vals[3] << 16);
  dst[2] = (unsigned int)vals[4] | ((unsigned int)vals[5] << 16);
  dst[3] = (unsigned int)vals[6] | ((unsigned int)vals[7] << 16);
}

// Block (256 thr, 4 waves): ch = bid&63, piece = bid>>6 (8 pieces), T0 = piece*32768.
// Wave w: W0 = T0 + 8192w, outputs out[W0 + 256i + 32c + j], c in [0,8).
// D_c[i][j] = sum_q A_q[i] . T[q-2c]; A frag (i=l31,h): x[W0-4000+256i+16q+8h+e].
// Window 16B-block beta = 1024w + 32i + 2q + h staged at LDS slot sigma(beta).
// A-reads: 2 contiguous 512B segments (conflict-free). Staging iterates sigma
// (contiguous LDS writes, conflict-free; global reads scattered, L1/L2 absorb).
// Main loop barrier-free: 8-MFMA clusters; A prefetch distance 2, B distance 4.
__global__ __launch_bounds__(256, 2) void conv_main(const float* __restrict__ x,
                                                    const unsigned short* __restrict__ btf,
                                                    float* __restrict__ out) {
  __shared__ alignas(16) unsigned char xs[NSLOT_W * 16];
  const int bid = blockIdx.x;
  const int ch = bid & 63;          // all 8 pieces of a channel share bid%8 -> same XCD
  const int T0 = (bid >> 6) << 15;
  const float* xch = x + (size_t)ch * T_LEN;
  const char* btc = (const char*)btf + (size_t)ch * NCHUNK * 1024;

  const int tid = threadIdx.x;
  const int lane = tid & 63;
  const int w = tid >> 6;

  // ---- A staging: iterate permuted slot sig (contiguous LDS writes).
  // sig = a + 145b (a<145, b<32) -> n = 32a + b; invalid n >= WBLK gets zeros.
  for (int sig = tid; sig < NSLOT_W; sig += 256) {
    int b = (int)((unsigned)sig / 145u);
    int a = sig - 145 * b;
    int n = 32 * a + b;
    float v0 = 0.f, v1 = 0.f, v2 = 0.f, v3 = 0.f, v4 = 0.f, v5 = 0.f, v6 = 0.f, v7 = 0.f;
    if (n < WBLK) {
      int gi = T0 - 4000 + 8 * n;
      if (gi >= 0 && gi + 8 <= T_LEN) {
        float4 va = *(const float4*)(xch + gi);
        float4 vb = *(const float4*)(xch + gi + 4);
        v0 = va.x; v1 = va.y; v2 = va.z; v3 = va.w;
        v4 = vb.x; v5 = vb.y; v6 = vb.z; v7 = vb.w;
      } else {
        v0 = (gi + 0 >= 0 && gi + 0 < T_LEN) ? xch[gi + 0] : 0.f;
        v1 = (gi + 1 >= 0 && gi + 1 < T_LEN) ? xch[gi + 1] : 0.f;
        v2 = (gi + 2 >= 0 && gi + 2 < T_LEN) ? xch[gi + 2] : 0.f;
        v3 = (gi + 3 >= 0 && gi + 3 < T_LEN) ? xch[gi + 3] : 0.f;
        v4 = (gi + 4 >= 0 && gi + 4 < T_LEN) ? xch[gi + 4] : 0.f;
        v5 = (gi + 5 >= 0 && gi + 5 < T_LEN) ? xch[gi + 5] : 0.f;
        v6 = (gi + 6 >= 0 && gi + 6 < T_LEN) ? xch[gi + 6] : 0.f;
        v7 = (gi + 7 >= 0 && gi + 7 < T_LEN) ? xch[gi + 7] : 0.f;
      }
    }
    uint4 pk;
    pk.x = (unsigned int)f2bf(v0) | ((unsigned int)f2bf(v1) << 16);
    pk.y = (unsigned int)f2bf(v2) | ((unsigned int)f2bf(v3) << 16);
    pk.z = (unsigned int)f2bf(v4) | ((unsigned int)f2bf(v5) << 16);
    pk.w = (unsigned int)f2bf(v6) | ((unsigned int)f2bf(v7) << 16);
    *(uint4*)(xs + 16 * sig) = pk;
  }
  __syncthreads();

  const int l31 = lane & 31;
  const int h = lane >> 5;
  // beta = 1024w + 32*l31 + 2q + h -> sigma = (32w + l31 + 145h) + (q>>4) + 290*(q&15)
  const unsigned abase = 16u * (unsigned)(32 * w + l31 + SIG_M * h);

  auto aread = [&](int q) -> bf16x8 {
    unsigned off = 16u * ((unsigned)(q >> 4) + 290u * (unsigned)(q & 15));
    return *(const bf16x8*)(xs + abase + off);
  };
  auto bloadz = [&](int t) -> bf16x8 {
    int tc = ((unsigned)t > 252u) ? 252 : t;   // negatives & >252 -> T[252] = zeros
    return *(const bf16x8*)(btc + (size_t)tc * 1024 + lane * 16);
  };

  f32x16 acc[8] = {};
  bf16x8 zero8 = {};
  // Ring state at step 0: E_c = T[-2c] (zeros for c>0), O_c = T[1-2c]
  bf16x8 E0 = bloadz(0), E1 = zero8, E2 = zero8, E3 = zero8,
         E4 = zero8, E5 = zero8, E6 = zero8, E7 = zero8;
  bf16x8 O0 = bloadz(1), O1 = zero8, O2 = zero8, O3 = zero8,
         O4 = zero8, O5 = zero8, O6 = zero8, O7 = zero8;
  bf16x8 pE = bloadz(2), pO = bloadz(3);   // queue: T[q+2] (distance 4 incl. in-flight nb)
  bf16x8 a_cur = aread(0), a_nxt = aread(1);

#define DO_STEP(R0, R1, R2, R3, R4, R5, R6, R7, PP, QQ)                                  \
  {                                                                                      \
    bf16x8 nb = bloadz((QQ) + 4);  /* B distance 4 q-steps */                            \
    bf16x8 an = aread((QQ) + 2);   /* A distance 2 */                                    \
    __builtin_amdgcn_s_setprio(1);                                                       \
    acc[0] = __builtin_amdgcn_mfma_f32_32x32x16_bf16(a_cur, R0, acc[0], 0, 0, 0);        \
    acc[1] = __builtin_amdgcn_mfma_f32_32x32x16_bf16(a_cur, R1, acc[1], 0, 0, 0);        \
    acc[2] = __builtin_amdgcn_mfma_f32_32x32x16_bf16(a_cur, R2, acc[2], 0, 0, 0);        \
    acc[3] = __builtin_amdgcn_mfma_f32_32x32x16_bf16(a_cur, R3, acc[3], 0, 0, 0);        \
    acc[4] = __builtin_amdgcn_mfma_f32_32x32x16_bf16(a_cur, R4, acc[4], 0, 0, 0);        \
    acc[5] = __builtin_amdgcn_mfma_f32_32x32x16_bf16(a_cur, R5, acc[5], 0, 0, 0);        \
    acc[6] = __builtin_amdgcn_mfma_f32_32x32x16_bf16(a_cur, R6, acc[6], 0, 0, 0);        \
    acc[7] = __builtin_amdgcn_mfma_f32_32x32x16_bf16(a_cur, R7, acc[7], 0, 0, 0);        \
    __builtin_amdgcn_s_setprio(0);                                                       \
    R7 = R6; R6 = R5; R5 = R4; R4 = R3; R3 = R2; R2 = R1; R1 = R0;                       \
    R0 = PP; PP = nb;                                                                    \
    a_cur = a_nxt; a_nxt = an;                                                           \
  }

#pragma unroll 8
  for (int q = 0; q < NSTEP; q += 2) {
    DO_STEP(E0, E1, E2, E3, E4, E5, E6, E7, pE, q);
    DO_STEP(O0, O1, O2, O3, O4, O5, O6, O7, pO, q + 1);
  }
#undef DO_STEP

  // C/D layout: col j = lane&31, row i = (r&3) + 8*(r>>2) + 4*h
  float* och = out + (size_t)ch * T_LEN + T0 + 8192 * w;
#pragma unroll
  for (int c = 0; c < 8; ++c) {
#pragma unroll
    for (int r = 0; r < 16; ++r) {
      int irow = (r & 3) + 8 * (r >> 2) + 4 * h;
      och[256 * irow + 32 * c + l31] = acc[c][r];
    }
  }
}

extern "C" void kernel_launch(void* const* d_in, const int* in_sizes, int n_in,
                              void* d_out, int out_size, void* d_ws, size_t ws_size,
                              hipStream_t stream) {
  const float* onsets  = (const float*)d_in[0];
  const float* sources = (const float*)d_in[1];
  unsigned short* btf  = (unsigned short*)d_ws;   // 64*253*64*8*2 = 16,580,608 B
  float* out = (float*)d_out;

  int nthr = NCH * NCHUNK * 64;
  build_btf<<<(nthr + 255) / 256, 256, 0, stream>>>(sources, btf);
  conv_main<<<512, 256, 0, stream>>>(onsets, btf, out);
}

// Round 11
// 116.291 us; speedup vs baseline: 1.4494x; 1.0394x over previous
//
#include <hip/hip_runtime.h>

#define T_LEN 262144
#define R_LEN 4000
#define NCH 64
#define NCHUNK 253       // B chunks t in [0,253); T[252] = zeros (clamp target)
#define WBLK 4616        // valid window 16B-blocks
#define SIG_M 145        // sigma(n) = (n>>5) + 145*(n&31), injective for n < 4640
#define NSLOT_W 4640     // sigma range; LDS = 4640*16 = 74240 B
#define NSTEP 272        // 17 x 16-step unrolled iterations; steps >= 266 hit T[252]=0

typedef __attribute__((ext_vector_type(8))) short bf16x8;
typedef __attribute__((ext_vector_type(16))) float f32x16;

static __device__ __forceinline__ unsigned short f2bf(float f) {
  unsigned u = __builtin_bit_cast(unsigned, f);
  unsigned r = 0x7FFFu + ((u >> 16) & 1u);
  return (unsigned short)((u + r) >> 16);
}

// T[t][j,h,e] = k[4000 + j - 16t - 8h - e] (zero outside [0,4000))
// stored: btf[((ch*253 + t)*64 + lane)*8 + e], j = lane&31, h = lane>>5
__global__ __launch_bounds__(256) void build_btf(const float* __restrict__ src,
                                                 unsigned short* __restrict__ btf) {
  int t0 = blockIdx.x * 256 + threadIdx.x;
  if (t0 >= NCH * NCHUNK * 64) return;
  int lane = t0 & 63;
  int t = (t0 >> 6) % NCHUNK;
  int ch = t0 / (64 * NCHUNK);
  int j = lane & 31;
  int h = lane >> 5;
  int kbase = 4000 + j - 16 * t - 8 * h;
  const float* k = src + (size_t)ch * R_LEN;
  unsigned short vals[8];
#pragma unroll
  for (int e = 0; e < 8; ++e) {
    int r = kbase - e;
    float f = (r >= 0 && r < R_LEN) ? k[r] : 0.0f;
    vals[e] = f2bf(f);
  }
  unsigned int* dst = (unsigned int*)(btf + (size_t)t0 * 8);
  dst[0] = (unsigned int)vals[0] | ((unsigned int)vals[1] << 16);
  dst[1] = (unsigned int)vals[2] | ((unsigned int)vals[3] << 16);
  dst[2] = (unsigned int)vals[4] | ((unsigned int)vals[5] << 16);
  dst[3] = (unsigned int)vals[6] | ((unsigned int)vals[7] << 16);
}

// Block (256 thr, 4 waves): ch = bid&63, piece = bid>>6 (8 pieces), T0 = piece*32768.
// Wave w: W0 = T0 + 8192w, outputs out[W0 + 256i + 32c + j], c in [0,8).
// D_c[i][j] = sum_q A_q[i] . T[q-2c]; A frag (i=l31,h): x[W0-4000+256i+16q+8h+e].
// Window 16B-block beta = 1024w + 32i + 2q + h at LDS slot sigma(beta); A-reads are
// 2 contiguous 512B segments (conflict-free).
// Main loop: ZERO-MOV rings. 8-slot E/O rings rotated by compile-time argument
// rotation (16-step unroll = full period); B-load writes the slot consumed as c=7
// this step (placed after the c=7 MFMA -> WAR-free, ~1-step in-flight). A uses a
// 4-slot static rotation (distance 2). No barriers, no shifts, no movs.
__global__ __launch_bounds__(256, 2) void conv_main(const float* __restrict__ x,
                                                    const unsigned short* __restrict__ btf,
                                                    float* __restrict__ out) {
  __shared__ alignas(16) unsigned char xs[NSLOT_W * 16];
  const int bid = blockIdx.x;
  const int ch = bid & 63;          // all 8 pieces of a channel share bid%8 -> same XCD
  const int T0 = (bid >> 6) << 15;
  const float* xch = x + (size_t)ch * T_LEN;
  const char* btc = (const char*)btf + (size_t)ch * NCHUNK * 1024;

  const int tid = threadIdx.x;
  const int lane = tid & 63;
  const int w = tid >> 6;

  // ---- A staging: iterate permuted slot sig (contiguous LDS writes).
  // sig = a + 145b (a<145, b<32) -> n = 32a + b; invalid n >= WBLK gets zeros.
  for (int sig = tid; sig < NSLOT_W; sig += 256) {
    int b = (int)((unsigned)sig / 145u);
    int a = sig - 145 * b;
    int n = 32 * a + b;
    float v0 = 0.f, v1 = 0.f, v2 = 0.f, v3 = 0.f, v4 = 0.f, v5 = 0.f, v6 = 0.f, v7 = 0.f;
    if (n < WBLK) {
      int gi = T0 - 4000 + 8 * n;
      if (gi >= 0 && gi + 8 <= T_LEN) {
        float4 va = *(const float4*)(xch + gi);
        float4 vb = *(const float4*)(xch + gi + 4);
        v0 = va.x; v1 = va.y; v2 = va.z; v3 = va.w;
        v4 = vb.x; v5 = vb.y; v6 = vb.z; v7 = vb.w;
      } else {
        v0 = (gi + 0 >= 0 && gi + 0 < T_LEN) ? xch[gi + 0] : 0.f;
        v1 = (gi + 1 >= 0 && gi + 1 < T_LEN) ? xch[gi + 1] : 0.f;
        v2 = (gi + 2 >= 0 && gi + 2 < T_LEN) ? xch[gi + 2] : 0.f;
        v3 = (gi + 3 >= 0 && gi + 3 < T_LEN) ? xch[gi + 3] : 0.f;
        v4 = (gi + 4 >= 0 && gi + 4 < T_LEN) ? xch[gi + 4] : 0.f;
        v5 = (gi + 5 >= 0 && gi + 5 < T_LEN) ? xch[gi + 5] : 0.f;
        v6 = (gi + 6 >= 0 && gi + 6 < T_LEN) ? xch[gi + 6] : 0.f;
        v7 = (gi + 7 >= 0 && gi + 7 < T_LEN) ? xch[gi + 7] : 0.f;
      }
    }
    uint4 pk;
    pk.x = (unsigned int)f2bf(v0) | ((unsigned int)f2bf(v1) << 16);
    pk.y = (unsigned int)f2bf(v2) | ((unsigned int)f2bf(v3) << 16);
    pk.z = (unsigned int)f2bf(v4) | ((unsigned int)f2bf(v5) << 16);
    pk.w = (unsigned int)f2bf(v6) | ((unsigned int)f2bf(v7) << 16);
    *(uint4*)(xs + 16 * sig) = pk;
  }
  __syncthreads();

  const int l31 = lane & 31;
  const int h = lane >> 5;
  // beta = 1024w + 32*l31 + 2q + h -> sigma = (32w + l31 + 145h) + (q>>4) + 290*(q&15)
  const unsigned abase = 16u * (unsigned)(32 * w + l31 + SIG_M * h);

  auto aread = [&](int q) -> bf16x8 {
    unsigned off = 16u * ((unsigned)(q >> 4) + 290u * (unsigned)(q & 15));
    return *(const bf16x8*)(xs + abase + off);
  };
  auto bloadz = [&](int t) -> bf16x8 {
    int tc = ((unsigned)t > 252u) ? 252 : t;   // negatives & >252 -> T[252] = zeros
    return *(const bf16x8*)(btc + (size_t)tc * 1024 + lane * 16);
  };

  f32x16 acc[8] = {};
  bf16x8 zero8 = {};
  // Even ring slots: at even step m, acc[c] consumes e[(m-c)&7]. Init (m=0):
  // e0 = T[0]; e7..e1 = T[-2]..T[-14] = 0. Odd ring likewise with T[1], zeros.
  bf16x8 e0 = bloadz(0), e1 = zero8, e2 = zero8, e3 = zero8,
         e4 = zero8, e5 = zero8, e6 = zero8, e7 = zero8;
  bf16x8 o0 = bloadz(1), o1 = zero8, o2 = zero8, o3 = zero8,
         o4 = zero8, o5 = zero8, o6 = zero8, o7 = zero8;
  // A slots: step q consumes a[q&3], writes aread(q+2) into a[(q+2)&3].
  bf16x8 a0 = aread(0), a1 = aread(1), a2 = zero8, a3 = zero8;

  // X0..X7 = operands for acc[0..7] (X7 = oldest, reloaded this step).
  // c=7 MFMA first, then its slot is overwritten by the load for step+2 (WAR-free).
#define STEP(X0, X1, X2, X3, X4, X5, X6, X7, AU, AD, QQ)                                 \
  {                                                                                      \
    AD = aread((QQ) + 2);                                                                \
    __builtin_amdgcn_s_setprio(1);                                                       \
    acc[7] = __builtin_amdgcn_mfma_f32_32x32x16_bf16(AU, X7, acc[7], 0, 0, 0);           \
    X7 = bloadz((QQ) + 2);                                                               \
    acc[0] = __builtin_amdgcn_mfma_f32_32x32x16_bf16(AU, X0, acc[0], 0, 0, 0);           \
    acc[1] = __builtin_amdgcn_mfma_f32_32x32x16_bf16(AU, X1, acc[1], 0, 0, 0);           \
    acc[2] = __builtin_amdgcn_mfma_f32_32x32x16_bf16(AU, X2, acc[2], 0, 0, 0);           \
    acc[3] = __builtin_amdgcn_mfma_f32_32x32x16_bf16(AU, X3, acc[3], 0, 0, 0);           \
    acc[4] = __builtin_amdgcn_mfma_f32_32x32x16_bf16(AU, X4, acc[4], 0, 0, 0);           \
    acc[5] = __builtin_amdgcn_mfma_f32_32x32x16_bf16(AU, X5, acc[5], 0, 0, 0);           \
    acc[6] = __builtin_amdgcn_mfma_f32_32x32x16_bf16(AU, X6, acc[6], 0, 0, 0);           \
    __builtin_amdgcn_s_setprio(0);                                                       \
  }

  for (int q = 0; q < NSTEP; q += 16) {
    STEP(e0, e7, e6, e5, e4, e3, e2, e1, a0, a2, q + 0);
    STEP(o0, o7, o6, o5, o4, o3, o2, o1, a1, a3, q + 1);
    STEP(e1, e0, e7, e6, e5, e4, e3, e2, a2, a0, q + 2);
    STEP(o1, o0, o7, o6, o5, o4, o3, o2, a3, a1, q + 3);
    STEP(e2, e1, e0, e7, e6, e5, e4, e3, a0, a2, q + 4);
    STEP(o2, o1, o0, o7, o6, o5, o4, o3, a1, a3, q + 5);
    STEP(e3, e2, e1, e0, e7, e6, e5, e4, a2, a0, q + 6);
    STEP(o3, o2, o1, o0, o7, o6, o5, o4, a3, a1, q + 7);
    STEP(e4, e3, e2, e1, e0, e7, e6, e5, a0, a2, q + 8);
    STEP(o4, o3, o2, o1, o0, o7, o6, o5, a1, a3, q + 9);
    STEP(e5, e4, e3, e2, e1, e0, e7, e6, a2, a0, q + 10);
    STEP(o5, o4, o3, o2, o1, o0, o7, o6, a3, a1, q + 11);
    STEP(e6, e5, e4, e3, e2, e1, e0, e7, a0, a2, q + 12);
    STEP(o6, o5, o4, o3, o2, o1, o0, o7, a1, a3, q + 13);
    STEP(e7, e6, e5, e4, e3, e2, e1, e0, a2, a0, q + 14);
    STEP(o7, o6, o5, o4, o3, o2, o1, o0, a3, a1, q + 15);
  }
#undef STEP

  // C/D layout: col j = lane&31, row i = (r&3) + 8*(r>>2) + 4*h
  float* och = out + (size_t)ch * T_LEN + T0 + 8192 * w;
#pragma unroll
  for (int c = 0; c < 8; ++c) {
#pragma unroll
    for (int r = 0; r < 16; ++r) {
      int irow = (r & 3) + 8 * (r >> 2) + 4 * h;
      och[256 * irow + 32 * c + l31] = acc[c][r];
    }
  }
}

extern "C" void kernel_launch(void* const* d_in, const int* in_sizes, int n_in,
                              void* d_out, int out_size, void* d_ws, size_t ws_size,
                              hipStream_t stream) {
  const float* onsets  = (const float*)d_in[0];
  const float* sources = (const float*)d_in[1];
  unsigned short* btf  = (unsigned short*)d_ws;   // 64*253*64*8*2 = 16,580,608 B
  float* out = (float*)d_out;

  int nthr = NCH * NCHUNK * 64;
  build_btf<<<(nthr + 255) / 256, 256, 0, stream>>>(sources, btf);
  conv_main<<<512, 256, 0, stream>>>(onsets, btf, out);
}